// Round 7
// baseline (146.025 us; speedup 1.0000x reference)
//
#include <hip/hip_runtime.h>
#include <hip/hip_bf16.h>
#include <math.h>

#define B_  2
#define NQ  13294
#define NK  13294
#define M_  (B_ * NK)   // 26588
#define MT  64
#define GX  ((M_ + MT - 1) / MT)  // 416

typedef __bf16 bf16x8 __attribute__((ext_vector_type(8)));
typedef float f32x4 __attribute__((ext_vector_type(4)));

static __device__ __forceinline__ f32x4 mfma16(bf16x8 a, bf16x8 b, f32x4 c) {
  return __builtin_amdgcn_mfma_f32_16x16x32_bf16(a, b, c, 0, 0, 0);
}

// ---- pack weights f32 [K=256][N] -> bf16 MFMA B-fragment layout ----
// bf16x8 slot g: lane=g&63, n_sub=(g>>6)&3, kt=(g>>8)&7, bn=g>>11
// n = bn*64 + n_sub*16 + (lane&15),  k = kt*32 + (lane>>4)*8 + j
static __device__ __forceinline__ void pack_one(
    const float* __restrict__ W1, const float* __restrict__ W2,
    int N1, int Ntot, __hip_bfloat16* __restrict__ out, int g) {
  int lane = g & 63;
  int n_sub = (g >> 6) & 3;
  int kt = (g >> 8) & 7;
  int bn = g >> 11;
  int n = bn * 64 + n_sub * 16 + (lane & 15);
  int k0 = kt * 32 + (lane >> 4) * 8;
  const float* src; int nn, Ns;
  if (n < N1) { src = W1; nn = n; Ns = N1; }
  else        { src = W2; nn = n - N1; Ns = Ntot - N1; }
  bf16x8 v;
#pragma unroll
  for (int j = 0; j < 8; ++j) v[j] = (__bf16)src[(size_t)(k0 + j) * Ns + nn];
  *(bf16x8*)(out + (size_t)g * 8) = v;
}

__global__ __launch_bounds__(256) void pack_all(
    const float* __restrict__ Wv, const float* __restrict__ Ws,
    const float* __restrict__ Wa, const float* __restrict__ Wo,
    __hip_bfloat16* __restrict__ wv_p, __hip_bfloat16* __restrict__ wsa_p,
    __hip_bfloat16* __restrict__ wo_p) {
  const int b = blockIdx.x, t = threadIdx.x;
  if (b < 32)       pack_one(Wv, Wv, 256, 256, wv_p,  b * 256 + t);
  else if (b < 80)  pack_one(Ws, Wa, 256, 384, wsa_p, (b - 32) * 256 + t);
  else              pack_one(Wo, Wo, 256, 256, wo_p,  (b - 80) * 256 + t);
}

// ---- unified 64-row-tile GEMM: C[M][N] = A[M][256] @ Wpack + bias ----
// mode 0: A=inpf(f32)  B=wv_p  N=256 out=value(bf16 row-major)
// mode 1: A=query(f32) B=wsa_p N=384 out=params(f32)
// mode 2: A=acc(bf16)  B=wo_p  N=256 out=out(f32)
// 256 threads / 4 waves; block stages A once; each wave owns whole 64-col
// slabs (nb = wid, wid+4, ...): 128 MFMA per 32 B-loads. Epilogue via
// wave-private 16x68 Cs chunks -> coalesced row stores. No barrier after stage.
#define CSTR 68

__global__ __launch_bounds__(256) void gemm_mt(
    const float* __restrict__ inpf, const float* __restrict__ query,
    const __hip_bfloat16* __restrict__ accin,
    const bf16x8* __restrict__ wv_p, const bf16x8* __restrict__ wsa_p,
    const bf16x8* __restrict__ wo_p,
    const float* __restrict__ bv, const float* __restrict__ bs,
    const float* __restrict__ ba, const float* __restrict__ bo,
    __hip_bfloat16* __restrict__ value, float* __restrict__ params,
    float* __restrict__ outp, int mode_base) {
  __shared__ bf16x8 As[8 * 4 * 64];        // 32 KB  [kt][sm][lane]
  __shared__ float  Cs[4 * 16 * CSTR];     // 17.4 KB, per-wave 16x68 chunk

  const int t = threadIdx.x;
  const int bm = blockIdx.x * MT;
  const int lane = t & 63, wid = t >> 6;
  const int mode = mode_base + blockIdx.y;

  // ---- stage A (64 rows x K=256) in fragment order ----
  {
    const int r = t >> 2;        // 0..63
    const int row = bm + r;
    const int sm = r >> 4;
    const int lb = r & 15;
    const bool ok = row < M_;
    if (mode != 2) {
      const float* Af = (mode == 0) ? inpf : query;
      const float* ap = Af + (size_t)row * 256 + (t & 3) * 64;
#pragma unroll
      for (int gi = 0; gi < 8; ++gi) {
        float4 u = make_float4(0.f,0.f,0.f,0.f), v = make_float4(0.f,0.f,0.f,0.f);
        if (ok) { u = *(const float4*)(ap + gi * 8); v = *(const float4*)(ap + gi * 8 + 4); }
        bf16x8 w;
        w[0]=(__bf16)u.x; w[1]=(__bf16)u.y; w[2]=(__bf16)u.z; w[3]=(__bf16)u.w;
        w[4]=(__bf16)v.x; w[5]=(__bf16)v.y; w[6]=(__bf16)v.z; w[7]=(__bf16)v.w;
        int k8 = (t & 3) * 8 + gi;
        As[((k8 >> 2) * 4 + sm) * 64 + lb + ((k8 & 3) << 4)] = w;
      }
    } else {
      const __hip_bfloat16* ap = accin + (size_t)row * 256 + (t & 3) * 64;
#pragma unroll
      for (int gi = 0; gi < 8; ++gi) {
        bf16x8 w = {};
        if (ok) w = *(const bf16x8*)(ap + gi * 8);
        int k8 = (t & 3) * 8 + gi;
        As[((k8 >> 2) * 4 + sm) * 64 + lb + ((k8 & 3) << 4)] = w;
      }
    }
  }
  __syncthreads();

  const bf16x8* Bp = (mode == 0) ? wv_p : (mode == 1) ? wsa_p : wo_p;
  const int NB = (mode == 1) ? 6 : 4;
  float* Cw = &Cs[wid * 16 * CSTR];

  for (int nb = wid; nb < NB; nb += 4) {
    const int colbase = nb * 64;
    const bf16x8* bpn = Bp + (size_t)nb * 2048;

    f32x4 acc[4][4] = {};
#pragma unroll
    for (int kt = 0; kt < 8; ++kt) {
      bf16x8 a0 = As[(kt * 4 + 0) * 64 + lane];
      bf16x8 a1 = As[(kt * 4 + 1) * 64 + lane];
      bf16x8 a2 = As[(kt * 4 + 2) * 64 + lane];
      bf16x8 a3 = As[(kt * 4 + 3) * 64 + lane];
#pragma unroll
      for (int n = 0; n < 4; ++n) {
        bf16x8 b = bpn[(kt * 4 + n) * 64 + lane];
        acc[0][n] = mfma16(a0, b, acc[0][n]);
        acc[1][n] = mfma16(a1, b, acc[1][n]);
        acc[2][n] = mfma16(a2, b, acc[2][n]);
        acc[3][n] = mfma16(a3, b, acc[3][n]);
      }
    }

    // epilogue: 4 chunks of 16 rows through wave-private Cs (same-wave, no barrier)
#pragma unroll
    for (int m = 0; m < 4; ++m) {
#pragma unroll
      for (int n = 0; n < 4; ++n)
#pragma unroll
        for (int rg = 0; rg < 4; ++rg)
          Cw[((lane >> 4) * 4 + rg) * CSTR + n * 16 + (lane & 15)] = acc[m][n][rg];

      const int lr = lane >> 2;
      const int c0 = (lane & 3) * 16;
      const int row = bm + m * 16 + lr;
      const int col = colbase + c0;
      float vv[16];
      *(float4*)&vv[0]  = *(float4*)&Cw[lr * CSTR + c0 + 0];
      *(float4*)&vv[4]  = *(float4*)&Cw[lr * CSTR + c0 + 4];
      *(float4*)&vv[8]  = *(float4*)&Cw[lr * CSTR + c0 + 8];
      *(float4*)&vv[12] = *(float4*)&Cw[lr * CSTR + c0 + 12];

      if (mode == 0) {
        const float* bias = bv + col;
        bf16x8 o0, o1;
#pragma unroll
        for (int j = 0; j < 8; ++j) {
          o0[j] = (__bf16)(vv[j] + bias[j]);
          o1[j] = (__bf16)(vv[8 + j] + bias[8 + j]);
        }
        if (row < M_) {
          *(bf16x8*)(value + (size_t)row * 256 + col + 0) = o0;
          *(bf16x8*)(value + (size_t)row * 256 + col + 8) = o1;
        }
      } else {
        float* Of = (mode == 1) ? params : outp;
        const int stride = (mode == 1) ? 384 : 256;
        const float* bias = (mode == 2) ? (bo + col)
                          : (col < 256 ? bs + col : ba + col - 256);
#pragma unroll
        for (int j = 0; j < 16; ++j) vv[j] += bias[j];
        if (row < M_) {
          float* dst = Of + (size_t)row * stride + col;
          *(float4*)(dst + 0)  = *(float4*)&vv[0];
          *(float4*)(dst + 4)  = *(float4*)&vv[4];
          *(float4*)(dst + 8)  = *(float4*)&vv[8];
          *(float4*)(dst + 12) = *(float4*)&vv[12];
        }
      }
    }
  }
}

// ---- sampler: softmax + bilinear combos + bf16 gather (key-major value) ----
// combo entry u32 = (bf16(weight)<<16) | key_idx ; region stride CS=65 words.
// Ping-pong regions (33.3 KB LDS total -> 4 blocks/CU, the R4 sweet spot) and
// one barrier per chunk.
#define CS 65

__global__ __launch_bounds__(256) void sampler(
    const float* __restrict__ refp, const float* __restrict__ params,
    const __hip_bfloat16* __restrict__ value, __hip_bfloat16* __restrict__ acc_out) {
  __shared__ unsigned int combo[2 * 64 * CS];  // 33.3 KB

  const int t = threadIdx.x;
  const int q0 = blockIdx.x * 16;
  const int bb = blockIdx.y;

  const int cqi = t >> 5;          // build: query 0..7
  const int chh = (t >> 2) & 7;    // build: head
  const int cl  = t & 3;           // build: level

  const int lane = t & 63;
  const int wid  = t >> 6;
  const int q2   = lane >> 5;
  const int gh   = (lane >> 2) & 7;
  const int gs   = lane & 3;
  // key-major: 512 B contiguous per key; uniform base + u32 voffset
  const char* vb = (const char*)value;
  const unsigned int voff0 = (unsigned int)bb * (NK * 512u) + (unsigned)(gh * 64 + gs * 16);

  const float DIMF[4]  = {100.f, 50.f, 25.f, 13.f};
  const int   LSTART[4] = {0, 10000, 12500, 13125};
  const float dimf  = DIMF[cl];
  const int   Wd    = (int)dimf;
  const int   lbase = LSTART[cl];

  for (int qc = 0; qc < 16; qc += 8) {
    unsigned int* reg = combo + ((qc >> 3) & 1) * (64 * CS);
    // ---- build: one thread per (q, head, level) ----
    {
      const int q = q0 + qc + cqi;
      const bool valid = q < NQ;
      const size_t row = (size_t)bb * NQ + (valid ? q : 0);
      const float* pr = params + row * 384;
      const float* lg = pr + 256 + chh * 16;
      float m = lg[0];
#pragma unroll
      for (int j = 1; j < 16; ++j) m = fmaxf(m, lg[j]);
      float s = 0.f;
#pragma unroll
      for (int j = 0; j < 16; ++j) s += __expf(lg[j] - m);
      const float inv = valid ? 1.f / s : 0.f;

      const float rx = refp[(row * 4 + cl) * 2 + 0];
      const float ry = refp[(row * 4 + cl) * 2 + 1];
      const float* of = pr + chh * 32 + cl * 8;
      unsigned int* cb = &reg[(cqi * 8 + chh) * CS + cl * 16];

#pragma unroll
      for (int p = 0; p < 4; ++p) {
        const float wa = __expf(lg[cl * 4 + p] - m) * inv;
        const float x = rx * dimf + of[p * 2 + 0] - 0.5f;
        const float y = ry * dimf + of[p * 2 + 1] - 0.5f;
        const float xf = floorf(x), yf = floorf(y);
        const float dx = x - xf, dy = y - yf;
        const int x0 = (int)xf, y0 = (int)yf;
        float w00 = (1.f - dx) * (1.f - dy) * wa;
        float w10 = dx * (1.f - dy) * wa;
        float w01 = (1.f - dx) * dy * wa;
        float w11 = dx * dy * wa;
        int i0, i1, i2, i3, xi, yi;
        xi = x0;     yi = y0;
        if (xi >= 0 && xi < Wd && yi >= 0 && yi < Wd) i0 = lbase + yi * Wd + xi; else { i0 = 0; w00 = 0.f; }
        xi = x0 + 1; yi = y0;
        if (xi >= 0 && xi < Wd && yi >= 0 && yi < Wd) i1 = lbase + yi * Wd + xi; else { i1 = 0; w10 = 0.f; }
        xi = x0;     yi = y0 + 1;
        if (xi >= 0 && xi < Wd && yi >= 0 && yi < Wd) i2 = lbase + yi * Wd + xi; else { i2 = 0; w01 = 0.f; }
        xi = x0 + 1; yi = y0 + 1;
        if (xi >= 0 && xi < Wd && yi >= 0 && yi < Wd) i3 = lbase + yi * Wd + xi; else { i3 = 0; w11 = 0.f; }
        cb[p * 4 + 0] = ((__float_as_uint(w00) + 0x8000u) & 0xffff0000u) | (unsigned)i0;
        cb[p * 4 + 1] = ((__float_as_uint(w10) + 0x8000u) & 0xffff0000u) | (unsigned)i1;
        cb[p * 4 + 2] = ((__float_as_uint(w01) + 0x8000u) & 0xffff0000u) | (unsigned)i2;
        cb[p * 4 + 3] = ((__float_as_uint(w11) + 0x8000u) & 0xffff0000u) | (unsigned)i3;
      }
    }
    __syncthreads();

    // ---- gather: wave wid covers queries {2*wid, 2*wid+1} of the chunk ----
    {
      const int qw = wid * 2 + q2;
      const int q = q0 + qc + qw;
      const unsigned int* cb = &reg[(qw * 8 + gh) * CS];
      float a0=0.f,a1=0.f,a2=0.f,a3=0.f,a4=0.f,a5=0.f,a6=0.f,a7=0.f;
#pragma unroll 8
      for (int e = 0; e < 64; ++e) {
        const unsigned int u = cb[e];
        const float w = __uint_as_float(u & 0xffff0000u);
        const unsigned int voff = voff0 + ((u & 0xffffu) << 9);
        const uint4 v = *(const uint4*)(vb + (size_t)voff);
        a0 += w * __uint_as_float(v.x << 16);
        a1 += w * __uint_as_float(v.x & 0xffff0000u);
        a2 += w * __uint_as_float(v.y << 16);
        a3 += w * __uint_as_float(v.y & 0xffff0000u);
        a4 += w * __uint_as_float(v.z << 16);
        a5 += w * __uint_as_float(v.z & 0xffff0000u);
        a6 += w * __uint_as_float(v.w << 16);
        a7 += w * __uint_as_float(v.w & 0xffff0000u);
      }
      if (q < NQ) {
        bf16x8 o;
        o[0]=(__bf16)a0; o[1]=(__bf16)a1; o[2]=(__bf16)a2; o[3]=(__bf16)a3;
        o[4]=(__bf16)a4; o[5]=(__bf16)a5; o[6]=(__bf16)a6; o[7]=(__bf16)a7;
        *(bf16x8*)((char*)acc_out + (((size_t)bb * NQ + q) * 256 + gh * 32 + gs * 8) * 2) = o;
      }
    }
  }
}

extern "C" void kernel_launch(void* const* d_in, const int* in_sizes, int n_in,
                              void* d_out, int out_size, void* d_ws, size_t ws_size,
                              hipStream_t stream) {
  const float* query = (const float*)d_in[0];
  const float* refp  = (const float*)d_in[1];
  const float* inpf  = (const float*)d_in[2];
  const float* Wv    = (const float*)d_in[3];
  const float* bv    = (const float*)d_in[4];
  const float* Ws    = (const float*)d_in[5];
  const float* bs    = (const float*)d_in[6];
  const float* Wa    = (const float*)d_in[7];
  const float* ba    = (const float*)d_in[8];
  const float* Wo    = (const float*)d_in[9];
  const float* bo    = (const float*)d_in[10];
  float* out = (float*)d_out;

  char* w = (char*)d_ws;
  __hip_bfloat16* value  = (__hip_bfloat16*)w;            w += (size_t)M_ * 256 * 2;  // key-major
  __hip_bfloat16* acc    = (__hip_bfloat16*)w;            w += (size_t)M_ * 256 * 2;
  float*          params = (float*)w;                     w += (size_t)M_ * 384 * 4;
  __hip_bfloat16* wv_p   = (__hip_bfloat16*)w;            w += 256 * 256 * 2;
  __hip_bfloat16* wsa_p  = (__hip_bfloat16*)w;            w += 256 * 384 * 2;
  __hip_bfloat16* wo_p   = (__hip_bfloat16*)w;

  pack_all<<<112, 256, 0, stream>>>(Wv, Ws, Wa, Wo, wv_p, wsa_p, wo_p);

  gemm_mt<<<dim3(GX, 2), 256, 0, stream>>>(
      inpf, query, acc, (const bf16x8*)wv_p, (const bf16x8*)wsa_p,
      (const bf16x8*)wo_p, bv, bs, ba, bo, value, params, out, 0);

  dim3 sgrid((NQ + 15) / 16, B_);
  sampler<<<sgrid, 256, 0, stream>>>(refp, params, value, acc);

  gemm_mt<<<dim3(GX, 1), 256, 0, stream>>>(
      inpf, query, acc, (const bf16x8*)wv_p, (const bf16x8*)wsa_p,
      (const bf16x8*)wo_p, bv, bs, ba, bo, value, params, out, 2);
}

// Round 8
// 126.907 us; speedup vs baseline: 1.1506x; 1.1506x over previous
//
#include <hip/hip_runtime.h>
#include <hip/hip_bf16.h>
#include <hip/hip_fp16.h>
#include <math.h>

#define B_  2
#define NQ  13294
#define NK  13294
#define M_  (B_ * NK)   // 26588
#define MT  32
#define GX  ((M_ + MT - 1) / MT)  // 831

typedef __bf16 bf16x8 __attribute__((ext_vector_type(8)));
typedef float f32x4 __attribute__((ext_vector_type(4)));

static __device__ __forceinline__ f32x4 mfma16(bf16x8 a, bf16x8 b, f32x4 c) {
  return __builtin_amdgcn_mfma_f32_16x16x32_bf16(a, b, c, 0, 0, 0);
}

// ---- pack weights f32 [K=256][N] -> bf16 MFMA B-fragment layout ----
// bf16x8 slot g: lane=g&63, n_sub=(g>>6)&3, kt=(g>>8)&7, bn=g>>11
// n = bn*64 + n_sub*16 + (lane&15),  k = kt*32 + (lane>>4)*8 + j
static __device__ __forceinline__ void pack_one(
    const float* __restrict__ W1, const float* __restrict__ W2,
    int N1, int Ntot, __hip_bfloat16* __restrict__ out, int g) {
  int lane = g & 63;
  int n_sub = (g >> 6) & 3;
  int kt = (g >> 8) & 7;
  int bn = g >> 11;
  int n = bn * 64 + n_sub * 16 + (lane & 15);
  int k0 = kt * 32 + (lane >> 4) * 8;
  const float* src; int nn, Ns;
  if (n < N1) { src = W1; nn = n; Ns = N1; }
  else        { src = W2; nn = n - N1; Ns = Ntot - N1; }
  bf16x8 v;
#pragma unroll
  for (int j = 0; j < 8; ++j) v[j] = (__bf16)src[(size_t)(k0 + j) * Ns + nn];
  *(bf16x8*)(out + (size_t)g * 8) = v;
}

__global__ __launch_bounds__(256) void pack_all(
    const float* __restrict__ Wv, const float* __restrict__ Ws,
    const float* __restrict__ Wa, const float* __restrict__ Wo,
    __hip_bfloat16* __restrict__ wv_p, __hip_bfloat16* __restrict__ wsa_p,
    __hip_bfloat16* __restrict__ wo_p) {
  const int b = blockIdx.x, t = threadIdx.x;
  if (b < 32)       pack_one(Wv, Wv, 256, 256, wv_p,  b * 256 + t);
  else if (b < 80)  pack_one(Ws, Wa, 256, 384, wsa_p, (b - 32) * 256 + t);
  else              pack_one(Wo, Wo, 256, 256, wo_p,  (b - 80) * 256 + t);
}

// ---- 32-row-tile GEMM (modes 0/1): C[M][N] = A[M][256] @ Wpack + bias ----
// mode 0: A=inpf(f32)  B=wv_p  N=256 out=value(bf16 row-major)
// mode 1: A=query(f32) B=wsa_p N=384 out=params(f16)
// 128 threads (2 waves); block stages A once, waves alternate 64-col slabs;
// epilogue via wave-private Cs transpose -> coalesced row stores.
#define CSTR 68

__global__ __launch_bounds__(128) void gemm_mt(
    const float* __restrict__ inpf, const float* __restrict__ query,
    const bf16x8* __restrict__ wv_p, const bf16x8* __restrict__ wsa_p,
    const float* __restrict__ bv, const float* __restrict__ bs,
    const float* __restrict__ ba,
    __hip_bfloat16* __restrict__ value, __half* __restrict__ params) {
  __shared__ bf16x8 As[8 * 2 * 64];        // 16 KB
  __shared__ float  Cs[2 * MT * CSTR];     // 17.4 KB

  const int t = threadIdx.x;
  const int bm = blockIdx.x * MT;
  const int lane = t & 63, wid = t >> 6;
  const int mode = blockIdx.y;

  // ---- stage A (32 rows x K=256) in fragment order ----
  {
    const int r = t >> 2;        // 0..31
    const int row = bm + r;
    const int sm = r >> 4;
    const int lb = r & 15;
    const bool ok = row < M_;
    const float* Af = (mode == 0) ? inpf : query;
    const float* ap = Af + (size_t)row * 256 + (t & 3) * 64;
#pragma unroll
    for (int gi = 0; gi < 8; ++gi) {
      float4 u = make_float4(0.f,0.f,0.f,0.f), v = make_float4(0.f,0.f,0.f,0.f);
      if (ok) { u = *(const float4*)(ap + gi * 8); v = *(const float4*)(ap + gi * 8 + 4); }
      bf16x8 w;
      w[0]=(__bf16)u.x; w[1]=(__bf16)u.y; w[2]=(__bf16)u.z; w[3]=(__bf16)u.w;
      w[4]=(__bf16)v.x; w[5]=(__bf16)v.y; w[6]=(__bf16)v.z; w[7]=(__bf16)v.w;
      int k8 = (t & 3) * 8 + gi;
      As[((k8 >> 2) * 2 + sm) * 64 + lb + ((k8 & 3) << 4)] = w;
    }
  }
  __syncthreads();

  const bf16x8* Bp = (mode == 0) ? wv_p : wsa_p;
  const int NB = (mode == 1) ? 6 : 4;
  float* Cw = &Cs[wid * MT * CSTR];

  for (int nb = wid; nb < NB; nb += 2) {
    const int colbase = nb * 64;
    const bf16x8* bpn = Bp + (size_t)nb * 2048;

    f32x4 acc[2][4] = {};
#pragma unroll
    for (int kt = 0; kt < 8; ++kt) {
      bf16x8 a0 = As[(kt * 2 + 0) * 64 + lane];
      bf16x8 a1 = As[(kt * 2 + 1) * 64 + lane];
#pragma unroll
      for (int n = 0; n < 4; ++n) {
        bf16x8 b = bpn[(kt * 4 + n) * 64 + lane];
        acc[0][n] = mfma16(a0, b, acc[0][n]);
        acc[1][n] = mfma16(a1, b, acc[1][n]);
      }
    }

    // fragment -> wave-private Cs (no block barrier needed)
#pragma unroll
    for (int m = 0; m < 2; ++m)
#pragma unroll
      for (int n = 0; n < 4; ++n)
#pragma unroll
        for (int rg = 0; rg < 4; ++rg)
          Cw[(m * 16 + (lane >> 4) * 4 + rg) * CSTR + n * 16 + (lane & 15)] = acc[m][n][rg];

    if (mode == 0) {
      // bf16 value, row-major: lane covers 8 cols, 8 rows/pass, 4 passes
#pragma unroll
      for (int p = 0; p < 4; ++p) {
        const int r = (lane >> 3) + p * 8;
        const int c = (lane & 7) * 8;
        const int row = bm + r;
        float4 u = *(float4*)&Cw[r * CSTR + c];
        float4 v = *(float4*)&Cw[r * CSTR + c + 4];
        const float* bias = bv + colbase + c;
        bf16x8 o;
        o[0]=(__bf16)(u.x+bias[0]); o[1]=(__bf16)(u.y+bias[1]);
        o[2]=(__bf16)(u.z+bias[2]); o[3]=(__bf16)(u.w+bias[3]);
        o[4]=(__bf16)(v.x+bias[4]); o[5]=(__bf16)(v.y+bias[5]);
        o[6]=(__bf16)(v.z+bias[6]); o[7]=(__bf16)(v.w+bias[7]);
        if (row < M_)
          *(bf16x8*)(value + (size_t)row * 256 + colbase + c) = o;
      }
    } else {
      // f16 params: lane covers 4 cols, 4 rows/pass, 8 passes
#pragma unroll
      for (int p = 0; p < 8; ++p) {
        const int r = (lane >> 4) + p * 4;
        const int c = (lane & 15) * 4;
        const int row = bm + r;
        const int col = colbase + c;
        float4 u = *(float4*)&Cw[r * CSTR + c];
        const float* bias = (col < 256) ? (bs + col) : (ba + col - 256);
        u.x += bias[0]; u.y += bias[1]; u.z += bias[2]; u.w += bias[3];
        if (row < M_) {
          __half2 h0 = __floats2half2_rn(u.x, u.y);
          __half2 h1 = __floats2half2_rn(u.z, u.w);
          uint2 st;
          st.x = *(unsigned int*)&h0;
          st.y = *(unsigned int*)&h1;
          *(uint2*)(params + (size_t)row * 384 + col) = st;
        }
      }
    }
  }
}

// ---- fused sampler: softmax + bilinear combos + bf16 gather + out-proj ----
// combo entry u32 = (bf16(weight)<<16) | key_idx ; region stride CS=65 words,
// ping-pong (33.3 KB). Gathered acc written to accs LDS [ch8][q] (A-fragment
// order), then M=16 MFMA GEMM vs wo_p (L2-hot) -> out. 41.4 KB LDS = 3 blk/CU.
#define CS 65

__global__ __launch_bounds__(256) void sampler(
    const float* __restrict__ refp, const __half* __restrict__ params,
    const __hip_bfloat16* __restrict__ value, const bf16x8* __restrict__ wo_p,
    const float* __restrict__ bo, float* __restrict__ outp) {
  __shared__ unsigned int combo[2 * 64 * CS];  // 33.3 KB
  __shared__ bf16x8 accs[32][16];              // 8 KB  [ch8][q_local]

  const int t = threadIdx.x;
  const int q0 = blockIdx.x * 16;
  const int bb = blockIdx.y;

  const int cqi = t >> 5;          // build: query 0..7
  const int chh = (t >> 2) & 7;    // build: head
  const int cl  = t & 3;           // build: level

  const int lane = t & 63;
  const int wid  = t >> 6;
  const int q2   = lane >> 5;
  const int gh   = (lane >> 2) & 7;
  const int gs   = lane & 3;
  // key-major: 512 B contiguous per key; uniform base + u32 voffset
  const char* vb = (const char*)value;
  const unsigned int voff0 = (unsigned int)bb * (NK * 512u) + (unsigned)(gh * 64 + gs * 16);

  const float DIMF[4]  = {100.f, 50.f, 25.f, 13.f};
  const int   LSTART[4] = {0, 10000, 12500, 13125};
  const float dimf  = DIMF[cl];
  const int   Wd    = (int)dimf;
  const int   lbase = LSTART[cl];

  for (int qc = 0; qc < 16; qc += 8) {
    unsigned int* reg = combo + ((qc >> 3) & 1) * (64 * CS);
    // ---- build: one thread per (q, head, level) ----
    {
      const int q = q0 + qc + cqi;
      const bool valid = q < NQ;
      const size_t row = (size_t)bb * NQ + (valid ? q : 0);
      const __half* pr = params + row * 384;

      union { uint4 u[2]; __half h[16]; } LG;
      LG.u[0] = *(const uint4*)(pr + 256 + chh * 16);
      LG.u[1] = *(const uint4*)(pr + 256 + chh * 16 + 8);
      float lgf[16];
#pragma unroll
      for (int j = 0; j < 16; ++j) lgf[j] = __half2float(LG.h[j]);
      float m = lgf[0];
#pragma unroll
      for (int j = 1; j < 16; ++j) m = fmaxf(m, lgf[j]);
      float s = 0.f;
#pragma unroll
      for (int j = 0; j < 16; ++j) s += __expf(lgf[j] - m);
      const float inv = valid ? 1.f / s : 0.f;

      const float rx = refp[(row * 4 + cl) * 2 + 0];
      const float ry = refp[(row * 4 + cl) * 2 + 1];
      union { uint4 u; __half h[8]; } OF;
      OF.u = *(const uint4*)(pr + chh * 32 + cl * 8);
      unsigned int* cb = &reg[(cqi * 8 + chh) * CS + cl * 16];

#pragma unroll
      for (int p = 0; p < 4; ++p) {
        const float wa = __expf(lgf[cl * 4 + p] - m) * inv;
        const float x = rx * dimf + __half2float(OF.h[p * 2 + 0]) - 0.5f;
        const float y = ry * dimf + __half2float(OF.h[p * 2 + 1]) - 0.5f;
        const float xf = floorf(x), yf = floorf(y);
        const float dx = x - xf, dy = y - yf;
        const int x0 = (int)xf, y0 = (int)yf;
        float w00 = (1.f - dx) * (1.f - dy) * wa;
        float w10 = dx * (1.f - dy) * wa;
        float w01 = (1.f - dx) * dy * wa;
        float w11 = dx * dy * wa;
        int i0, i1, i2, i3, xi, yi;
        xi = x0;     yi = y0;
        if (xi >= 0 && xi < Wd && yi >= 0 && yi < Wd) i0 = lbase + yi * Wd + xi; else { i0 = 0; w00 = 0.f; }
        xi = x0 + 1; yi = y0;
        if (xi >= 0 && xi < Wd && yi >= 0 && yi < Wd) i1 = lbase + yi * Wd + xi; else { i1 = 0; w10 = 0.f; }
        xi = x0;     yi = y0 + 1;
        if (xi >= 0 && xi < Wd && yi >= 0 && yi < Wd) i2 = lbase + yi * Wd + xi; else { i2 = 0; w01 = 0.f; }
        xi = x0 + 1; yi = y0 + 1;
        if (xi >= 0 && xi < Wd && yi >= 0 && yi < Wd) i3 = lbase + yi * Wd + xi; else { i3 = 0; w11 = 0.f; }
        cb[p * 4 + 0] = ((__float_as_uint(w00) + 0x8000u) & 0xffff0000u) | (unsigned)i0;
        cb[p * 4 + 1] = ((__float_as_uint(w10) + 0x8000u) & 0xffff0000u) | (unsigned)i1;
        cb[p * 4 + 2] = ((__float_as_uint(w01) + 0x8000u) & 0xffff0000u) | (unsigned)i2;
        cb[p * 4 + 3] = ((__float_as_uint(w11) + 0x8000u) & 0xffff0000u) | (unsigned)i3;
      }
    }
    __syncthreads();

    // ---- gather: wave wid covers queries {2*wid, 2*wid+1} of the chunk ----
    {
      const int qw = wid * 2 + q2;
      const unsigned int* cb = &reg[(qw * 8 + gh) * CS];
      float a0=0.f,a1=0.f,a2=0.f,a3=0.f,a4=0.f,a5=0.f,a6=0.f,a7=0.f;
#pragma unroll 8
      for (int e = 0; e < 64; ++e) {
        const unsigned int u = cb[e];
        const float w = __uint_as_float(u & 0xffff0000u);
        const unsigned int voff = voff0 + ((u & 0xffffu) << 9);
        const uint4 v = *(const uint4*)(vb + (size_t)voff);
        a0 += w * __uint_as_float(v.x << 16);
        a1 += w * __uint_as_float(v.x & 0xffff0000u);
        a2 += w * __uint_as_float(v.y << 16);
        a3 += w * __uint_as_float(v.y & 0xffff0000u);
        a4 += w * __uint_as_float(v.z << 16);
        a5 += w * __uint_as_float(v.z & 0xffff0000u);
        a6 += w * __uint_as_float(v.w << 16);
        a7 += w * __uint_as_float(v.w & 0xffff0000u);
      }
      bf16x8 o;
      o[0]=(__bf16)a0; o[1]=(__bf16)a1; o[2]=(__bf16)a2; o[3]=(__bf16)a3;
      o[4]=(__bf16)a4; o[5]=(__bf16)a5; o[6]=(__bf16)a6; o[7]=(__bf16)a7;
      accs[gh * 4 + gs][qc + qw] = o;
    }
  }
  __syncthreads();

  // ---- fused out-projection: out[16 x 256] = accs @ Wo + bo ----
  // wave wid owns cols wid*64..+63 ; A-frag: q = lane&15, k-sub = lane>>4
  {
    const bf16x8* bpn = wo_p + (size_t)wid * 2048;
    f32x4 oacc[4] = {};
#pragma unroll
    for (int kt = 0; kt < 8; ++kt) {
      bf16x8 a = accs[kt * 4 + (lane >> 4)][lane & 15];
#pragma unroll
      for (int n = 0; n < 4; ++n)
        oacc[n] = mfma16(a, bpn[(kt * 4 + n) * 64 + lane], oacc[n]);
    }
#pragma unroll
    for (int n = 0; n < 4; ++n) {
      const int col = wid * 64 + n * 16 + (lane & 15);
      const float bias = bo[col];
#pragma unroll
      for (int rg = 0; rg < 4; ++rg) {
        const int ql = (lane >> 4) * 4 + rg;
        const int q = q0 + ql;
        if (q < NQ)
          outp[((size_t)bb * NQ + q) * 256 + col] = oacc[n][rg] + bias;
      }
    }
  }
}

extern "C" void kernel_launch(void* const* d_in, const int* in_sizes, int n_in,
                              void* d_out, int out_size, void* d_ws, size_t ws_size,
                              hipStream_t stream) {
  const float* query = (const float*)d_in[0];
  const float* refp  = (const float*)d_in[1];
  const float* inpf  = (const float*)d_in[2];
  const float* Wv    = (const float*)d_in[3];
  const float* bv    = (const float*)d_in[4];
  const float* Ws    = (const float*)d_in[5];
  const float* bs    = (const float*)d_in[6];
  const float* Wa    = (const float*)d_in[7];
  const float* ba    = (const float*)d_in[8];
  const float* Wo    = (const float*)d_in[9];
  const float* bo    = (const float*)d_in[10];
  float* out = (float*)d_out;

  char* w = (char*)d_ws;
  __hip_bfloat16* value  = (__hip_bfloat16*)w;            w += (size_t)M_ * 256 * 2;  // key-major
  __half*         params = (__half*)w;                    w += (size_t)M_ * 384 * 2;
  __hip_bfloat16* wv_p   = (__hip_bfloat16*)w;            w += 256 * 256 * 2;
  __hip_bfloat16* wsa_p  = (__hip_bfloat16*)w;            w += 256 * 384 * 2;
  __hip_bfloat16* wo_p   = (__hip_bfloat16*)w;

  pack_all<<<112, 256, 0, stream>>>(Wv, Ws, Wa, Wo, wv_p, wsa_p, wo_p);

  gemm_mt<<<dim3(GX, 2), 128, 0, stream>>>(
      inpf, query, (const bf16x8*)wv_p, (const bf16x8*)wsa_p,
      bv, bs, ba, value, params);

  dim3 sgrid((NQ + 15) / 16, B_);
  sampler<<<sgrid, 256, 0, stream>>>(refp, params, value,
                                     (const bf16x8*)wo_p, bo, out);
}

// Round 9
// 126.838 us; speedup vs baseline: 1.1513x; 1.0005x over previous
//
#include <hip/hip_runtime.h>
#include <hip/hip_bf16.h>
#include <hip/hip_fp16.h>
#include <math.h>

#define B_  2
#define NQ  13294
#define NK  13294
#define M_  (B_ * NK)   // 26588
#define MT  32
#define GX  ((M_ + MT - 1) / MT)  // 831

typedef __bf16 bf16x8 __attribute__((ext_vector_type(8)));
typedef float f32x4 __attribute__((ext_vector_type(4)));

static __device__ __forceinline__ f32x4 mfma16(bf16x8 a, bf16x8 b, f32x4 c) {
  return __builtin_amdgcn_mfma_f32_16x16x32_bf16(a, b, c, 0, 0, 0);
}

// ---- pack weights f32 [K=256][N] -> bf16 MFMA B-fragment layout ----
// bf16x8 slot g: lane=g&63, n_sub=(g>>6)&3, kt=(g>>8)&7, bn=g>>11
// n = bn*64 + n_sub*16 + (lane&15),  k = kt*32 + (lane>>4)*8 + j
static __device__ __forceinline__ void pack_one(
    const float* __restrict__ W1, const float* __restrict__ W2,
    int N1, int Ntot, __hip_bfloat16* __restrict__ out, int g) {
  int lane = g & 63;
  int n_sub = (g >> 6) & 3;
  int kt = (g >> 8) & 7;
  int bn = g >> 11;
  int n = bn * 64 + n_sub * 16 + (lane & 15);
  int k0 = kt * 32 + (lane >> 4) * 8;
  const float* src; int nn, Ns;
  if (n < N1) { src = W1; nn = n; Ns = N1; }
  else        { src = W2; nn = n - N1; Ns = Ntot - N1; }
  bf16x8 v;
#pragma unroll
  for (int j = 0; j < 8; ++j) v[j] = (__bf16)src[(size_t)(k0 + j) * Ns + nn];
  *(bf16x8*)(out + (size_t)g * 8) = v;
}

__global__ __launch_bounds__(256) void pack_all(
    const float* __restrict__ Wv, const float* __restrict__ Ws,
    const float* __restrict__ Wa, const float* __restrict__ Wo,
    __hip_bfloat16* __restrict__ wv_p, __hip_bfloat16* __restrict__ wsa_p,
    __hip_bfloat16* __restrict__ wo_p) {
  const int b = blockIdx.x, t = threadIdx.x;
  if (b < 32)       pack_one(Wv, Wv, 256, 256, wv_p,  b * 256 + t);
  else if (b < 80)  pack_one(Ws, Wa, 256, 384, wsa_p, (b - 32) * 256 + t);
  else              pack_one(Wo, Wo, 256, 256, wo_p,  (b - 80) * 256 + t);
}

// ---- 32-row-tile GEMM (modes 0/1): C[M][N] = A[M][256] @ Wpack + bias ----
// mode 0: A=inpf(f32)  B=wv_p  N=256 out=value(bf16 row-major)
// mode 1: A=query(f32) B=wsa_p N=384 out=params(f16)
// 128 threads (2 waves); block stages A once, waves alternate 64-col slabs;
// epilogue via wave-private Cs transpose -> coalesced row stores.
#define CSTR 68

__global__ __launch_bounds__(128) void gemm_mt(
    const float* __restrict__ inpf, const float* __restrict__ query,
    const bf16x8* __restrict__ wv_p, const bf16x8* __restrict__ wsa_p,
    const float* __restrict__ bv, const float* __restrict__ bs,
    const float* __restrict__ ba,
    __hip_bfloat16* __restrict__ value, __half* __restrict__ params) {
  __shared__ bf16x8 As[8 * 2 * 64];        // 16 KB
  __shared__ float  Cs[2 * MT * CSTR];     // 17.4 KB

  const int t = threadIdx.x;
  const int bm = blockIdx.x * MT;
  const int lane = t & 63, wid = t >> 6;
  const int mode = blockIdx.y;

  // ---- stage A (32 rows x K=256) in fragment order ----
  {
    const int r = t >> 2;        // 0..31
    const int row = bm + r;
    const int sm = r >> 4;
    const int lb = r & 15;
    const bool ok = row < M_;
    const float* Af = (mode == 0) ? inpf : query;
    const float* ap = Af + (size_t)row * 256 + (t & 3) * 64;
#pragma unroll
    for (int gi = 0; gi < 8; ++gi) {
      float4 u = make_float4(0.f,0.f,0.f,0.f), v = make_float4(0.f,0.f,0.f,0.f);
      if (ok) { u = *(const float4*)(ap + gi * 8); v = *(const float4*)(ap + gi * 8 + 4); }
      bf16x8 w;
      w[0]=(__bf16)u.x; w[1]=(__bf16)u.y; w[2]=(__bf16)u.z; w[3]=(__bf16)u.w;
      w[4]=(__bf16)v.x; w[5]=(__bf16)v.y; w[6]=(__bf16)v.z; w[7]=(__bf16)v.w;
      int k8 = (t & 3) * 8 + gi;
      As[((k8 >> 2) * 2 + sm) * 64 + lb + ((k8 & 3) << 4)] = w;
    }
  }
  __syncthreads();

  const bf16x8* Bp = (mode == 0) ? wv_p : wsa_p;
  const int NB = (mode == 1) ? 6 : 4;
  float* Cw = &Cs[wid * MT * CSTR];

  for (int nb = wid; nb < NB; nb += 2) {
    const int colbase = nb * 64;
    const bf16x8* bpn = Bp + (size_t)nb * 2048;

    f32x4 acc[2][4] = {};
#pragma unroll
    for (int kt = 0; kt < 8; ++kt) {
      bf16x8 a0 = As[(kt * 2 + 0) * 64 + lane];
      bf16x8 a1 = As[(kt * 2 + 1) * 64 + lane];
#pragma unroll
      for (int n = 0; n < 4; ++n) {
        bf16x8 b = bpn[(kt * 4 + n) * 64 + lane];
        acc[0][n] = mfma16(a0, b, acc[0][n]);
        acc[1][n] = mfma16(a1, b, acc[1][n]);
      }
    }

    // fragment -> wave-private Cs (no block barrier needed)
#pragma unroll
    for (int m = 0; m < 2; ++m)
#pragma unroll
      for (int n = 0; n < 4; ++n)
#pragma unroll
        for (int rg = 0; rg < 4; ++rg)
          Cw[(m * 16 + (lane >> 4) * 4 + rg) * CSTR + n * 16 + (lane & 15)] = acc[m][n][rg];

    if (mode == 0) {
#pragma unroll
      for (int p = 0; p < 4; ++p) {
        const int r = (lane >> 3) + p * 8;
        const int c = (lane & 7) * 8;
        const int row = bm + r;
        float4 u = *(float4*)&Cw[r * CSTR + c];
        float4 v = *(float4*)&Cw[r * CSTR + c + 4];
        const float* bias = bv + colbase + c;
        bf16x8 o;
        o[0]=(__bf16)(u.x+bias[0]); o[1]=(__bf16)(u.y+bias[1]);
        o[2]=(__bf16)(u.z+bias[2]); o[3]=(__bf16)(u.w+bias[3]);
        o[4]=(__bf16)(v.x+bias[4]); o[5]=(__bf16)(v.y+bias[5]);
        o[6]=(__bf16)(v.z+bias[6]); o[7]=(__bf16)(v.w+bias[7]);
        if (row < M_)
          *(bf16x8*)(value + (size_t)row * 256 + colbase + c) = o;
      }
    } else {
#pragma unroll
      for (int p = 0; p < 8; ++p) {
        const int r = (lane >> 4) + p * 4;
        const int c = (lane & 15) * 4;
        const int row = bm + r;
        const int col = colbase + c;
        float4 u = *(float4*)&Cw[r * CSTR + c];
        const float* bias = (col < 256) ? (bs + col) : (ba + col - 256);
        u.x += bias[0]; u.y += bias[1]; u.z += bias[2]; u.w += bias[3];
        if (row < M_) {
          __half2 h0 = __floats2half2_rn(u.x, u.y);
          __half2 h1 = __floats2half2_rn(u.z, u.w);
          uint2 st;
          st.x = *(unsigned int*)&h0;
          st.y = *(unsigned int*)&h1;
          *(uint2*)(params + (size_t)row * 384 + col) = st;
        }
      }
    }
  }
}

// ---- fused sampler: softmax + bilinear combos + bf16 gather + out-proj ----
// combo entry u32 = (bf16(weight)<<16) | key_idx ; region stride CS=65,
// ping-pong halves (33.3 KB total -> 4 blocks/CU). After a wave's gather
// consumes region (qw*8+gh), its 4 gs-lanes store the bf16x8 acc into that
// region's dead entry slots (alignment-shifted) -- no separate accs buffer.
// Final phase: M=16 MFMA out-projection vs L2-hot wo_p.
#define CS 65
#define REGH (64 * CS)   // u32s per ping-pong half

__global__ __launch_bounds__(256) void sampler(
    const float* __restrict__ refp, const __half* __restrict__ params,
    const __hip_bfloat16* __restrict__ value, const bf16x8* __restrict__ wo_p,
    const float* __restrict__ bo, float* __restrict__ outp) {
  __shared__ unsigned int combo[2 * REGH];  // 33.3 KB

  const int t = threadIdx.x;
  const int q0 = blockIdx.x * 16;
  const int bb = blockIdx.y;

  const int cqi = t >> 5;          // build: query 0..7
  const int chh = (t >> 2) & 7;    // build: head
  const int cl  = t & 3;           // build: level

  const int lane = t & 63;
  const int wid  = t >> 6;
  const int q2   = lane >> 5;
  const int gh   = (lane >> 2) & 7;
  const int gs   = lane & 3;
  // key-major: 512 B contiguous per key; uniform base + u32 voffset
  const char* vb = (const char*)value;
  const unsigned int voff0 = (unsigned int)bb * (NK * 512u) + (unsigned)(gh * 64 + gs * 16);

  const float DIMF[4]  = {100.f, 50.f, 25.f, 13.f};
  const int   LSTART[4] = {0, 10000, 12500, 13125};
  const float dimf  = DIMF[cl];
  const int   Wd    = (int)dimf;
  const int   lbase = LSTART[cl];

  for (int qc = 0; qc < 16; qc += 8) {
    unsigned int* reg = combo + ((qc >> 3) & 1) * REGH;
    // ---- build: one thread per (q, head, level) ----
    {
      const int q = q0 + qc + cqi;
      const bool valid = q < NQ;
      const size_t row = (size_t)bb * NQ + (valid ? q : 0);
      const __half* pr = params + row * 384;

      union { uint4 u[2]; __half h[16]; } LG;
      LG.u[0] = *(const uint4*)(pr + 256 + chh * 16);
      LG.u[1] = *(const uint4*)(pr + 256 + chh * 16 + 8);
      float lgf[16];
#pragma unroll
      for (int j = 0; j < 16; ++j) lgf[j] = __half2float(LG.h[j]);
      float m = lgf[0];
#pragma unroll
      for (int j = 1; j < 16; ++j) m = fmaxf(m, lgf[j]);
      float s = 0.f;
#pragma unroll
      for (int j = 0; j < 16; ++j) s += __expf(lgf[j] - m);
      const float inv = valid ? 1.f / s : 0.f;

      const float rx = refp[(row * 4 + cl) * 2 + 0];
      const float ry = refp[(row * 4 + cl) * 2 + 1];
      union { uint4 u; __half h[8]; } OF;
      OF.u = *(const uint4*)(pr + chh * 32 + cl * 8);
      unsigned int* cb = &reg[(cqi * 8 + chh) * CS + cl * 16];

#pragma unroll
      for (int p = 0; p < 4; ++p) {
        const float wa = __expf(lgf[cl * 4 + p] - m) * inv;
        const float x = rx * dimf + __half2float(OF.h[p * 2 + 0]) - 0.5f;
        const float y = ry * dimf + __half2float(OF.h[p * 2 + 1]) - 0.5f;
        const float xf = floorf(x), yf = floorf(y);
        const float dx = x - xf, dy = y - yf;
        const int x0 = (int)xf, y0 = (int)yf;
        float w00 = (1.f - dx) * (1.f - dy) * wa;
        float w10 = dx * (1.f - dy) * wa;
        float w01 = (1.f - dx) * dy * wa;
        float w11 = dx * dy * wa;
        int i0, i1, i2, i3, xi, yi;
        xi = x0;     yi = y0;
        if (xi >= 0 && xi < Wd && yi >= 0 && yi < Wd) i0 = lbase + yi * Wd + xi; else { i0 = 0; w00 = 0.f; }
        xi = x0 + 1; yi = y0;
        if (xi >= 0 && xi < Wd && yi >= 0 && yi < Wd) i1 = lbase + yi * Wd + xi; else { i1 = 0; w10 = 0.f; }
        xi = x0;     yi = y0 + 1;
        if (xi >= 0 && xi < Wd && yi >= 0 && yi < Wd) i2 = lbase + yi * Wd + xi; else { i2 = 0; w01 = 0.f; }
        xi = x0 + 1; yi = y0 + 1;
        if (xi >= 0 && xi < Wd && yi >= 0 && yi < Wd) i3 = lbase + yi * Wd + xi; else { i3 = 0; w11 = 0.f; }
        cb[p * 4 + 0] = ((__float_as_uint(w00) + 0x8000u) & 0xffff0000u) | (unsigned)i0;
        cb[p * 4 + 1] = ((__float_as_uint(w10) + 0x8000u) & 0xffff0000u) | (unsigned)i1;
        cb[p * 4 + 2] = ((__float_as_uint(w01) + 0x8000u) & 0xffff0000u) | (unsigned)i2;
        cb[p * 4 + 3] = ((__float_as_uint(w11) + 0x8000u) & 0xffff0000u) | (unsigned)i3;
      }
    }
    __syncthreads();

    // ---- gather: wave wid covers queries {2*wid, 2*wid+1} of the chunk ----
    {
      const int qw = wid * 2 + q2;
      const int rr = qw * 8 + gh;               // this lane group's region
      const unsigned int* cb = &reg[rr * CS];
      float a0=0.f,a1=0.f,a2=0.f,a3=0.f,a4=0.f,a5=0.f,a6=0.f,a7=0.f;
#pragma unroll 8
      for (int e = 0; e < 64; ++e) {
        const unsigned int u = cb[e];
        const float w = __uint_as_float(u & 0xffff0000u);
        const unsigned int voff = voff0 + ((u & 0xffffu) << 9);
        const uint4 v = *(const uint4*)(vb + (size_t)voff);
        a0 += w * __uint_as_float(v.x << 16);
        a1 += w * __uint_as_float(v.x & 0xffff0000u);
        a2 += w * __uint_as_float(v.y << 16);
        a3 += w * __uint_as_float(v.y & 0xffff0000u);
        a4 += w * __uint_as_float(v.z << 16);
        a5 += w * __uint_as_float(v.z & 0xffff0000u);
        a6 += w * __uint_as_float(v.w << 16);
        a7 += w * __uint_as_float(v.w & 0xffff0000u);
      }
      // store acc into this region's (now dead) entries, 16B-aligned
      bf16x8 o;
      o[0]=(__bf16)a0; o[1]=(__bf16)a1; o[2]=(__bf16)a2; o[3]=(__bf16)a3;
      o[4]=(__bf16)a4; o[5]=(__bf16)a5; o[6]=(__bf16)a6; o[7]=(__bf16)a7;
      const int s = (4 - (rr & 3)) & 3;
      *(bf16x8*)(&reg[rr * CS + s + gs * 4]) = o;
    }
  }
  __syncthreads();

  // ---- fused out-projection: out[16 x 256] = accs @ Wo + bo ----
  // A-frag for local query ql = lane&15, k-sub hi = lane>>4:
  //   ch8 = kt*4 + hi ; acc lives in half (ql>>3), region (ql&7)*8 + kt,
  //   u32 offset ((4 - (kt&3)) & 3) + hi*4.
  {
    const unsigned int* abase = combo + ((lane >> 3) & 1) * REGH
                              + (lane & 7) * (8 * CS) + (lane >> 4) * 4;
    const bf16x8* bpn = wo_p + (size_t)wid * 2048;
    f32x4 oacc[4] = {};
#pragma unroll
    for (int kt = 0; kt < 8; ++kt) {
      const int s = (4 - (kt & 3)) & 3;
      bf16x8 a = *(const bf16x8*)(abase + kt * CS + s);
#pragma unroll
      for (int n = 0; n < 4; ++n)
        oacc[n] = mfma16(a, bpn[(kt * 4 + n) * 64 + lane], oacc[n]);
    }
#pragma unroll
    for (int n = 0; n < 4; ++n) {
      const int col = wid * 64 + n * 16 + (lane & 15);
      const float bias = bo[col];
#pragma unroll
      for (int rg = 0; rg < 4; ++rg) {
        const int ql = (lane >> 4) * 4 + rg;
        const int q = q0 + ql;
        if (q < NQ)
          outp[((size_t)bb * NQ + q) * 256 + col] = oacc[n][rg] + bias;
      }
    }
  }
}

extern "C" void kernel_launch(void* const* d_in, const int* in_sizes, int n_in,
                              void* d_out, int out_size, void* d_ws, size_t ws_size,
                              hipStream_t stream) {
  const float* query = (const float*)d_in[0];
  const float* refp  = (const float*)d_in[1];
  const float* inpf  = (const float*)d_in[2];
  const float* Wv    = (const float*)d_in[3];
  const float* bv    = (const float*)d_in[4];
  const float* Ws    = (const float*)d_in[5];
  const float* bs    = (const float*)d_in[6];
  const float* Wa    = (const float*)d_in[7];
  const float* ba    = (const float*)d_in[8];
  const float* Wo    = (const float*)d_in[9];
  const float* bo    = (const float*)d_in[10];
  float* out = (float*)d_out;

  char* w = (char*)d_ws;
  __hip_bfloat16* value  = (__hip_bfloat16*)w;            w += (size_t)M_ * 256 * 2;  // key-major
  __half*         params = (__half*)w;                    w += (size_t)M_ * 384 * 2;
  __hip_bfloat16* wv_p   = (__hip_bfloat16*)w;            w += 256 * 256 * 2;
  __hip_bfloat16* wsa_p  = (__hip_bfloat16*)w;            w += 256 * 384 * 2;
  __hip_bfloat16* wo_p   = (__hip_bfloat16*)w;

  pack_all<<<112, 256, 0, stream>>>(Wv, Ws, Wa, Wo, wv_p, wsa_p, wo_p);

  gemm_mt<<<dim3(GX, 2), 128, 0, stream>>>(
      inpf, query, (const bf16x8*)wv_p, (const bf16x8*)wsa_p,
      bv, bs, ba, value, params);

  dim3 sgrid((NQ + 15) / 16, B_);
  sampler<<<sgrid, 256, 0, stream>>>(refp, params, value,
                                     (const bf16x8*)wo_p, bo, out);
}

// Round 10
// 115.910 us; speedup vs baseline: 1.2598x; 1.0943x over previous
//
#include <hip/hip_runtime.h>
#include <hip/hip_bf16.h>
#include <hip/hip_fp16.h>
#include <math.h>

#define B_  2
#define NQ  13294
#define NK  13294
#define M_  (B_ * NK)   // 26588
#define MT  32
#define GX  ((M_ + MT - 1) / MT)  // 831

typedef __bf16 bf16x8 __attribute__((ext_vector_type(8)));
typedef float f32x4 __attribute__((ext_vector_type(4)));

static __device__ __forceinline__ f32x4 mfma16(bf16x8 a, bf16x8 b, f32x4 c) {
  return __builtin_amdgcn_mfma_f32_16x16x32_bf16(a, b, c, 0, 0, 0);
}

// ---- pack weights f32 [K=256][N] -> bf16 MFMA B-fragment layout ----
static __device__ __forceinline__ void pack_one(
    const float* __restrict__ W1, const float* __restrict__ W2,
    int N1, int Ntot, __hip_bfloat16* __restrict__ out, int g) {
  int lane = g & 63;
  int n_sub = (g >> 6) & 3;
  int kt = (g >> 8) & 7;
  int bn = g >> 11;
  int n = bn * 64 + n_sub * 16 + (lane & 15);
  int k0 = kt * 32 + (lane >> 4) * 8;
  const float* src; int nn, Ns;
  if (n < N1) { src = W1; nn = n; Ns = N1; }
  else        { src = W2; nn = n - N1; Ns = Ntot - N1; }
  bf16x8 v;
#pragma unroll
  for (int j = 0; j < 8; ++j) v[j] = (__bf16)src[(size_t)(k0 + j) * Ns + nn];
  *(bf16x8*)(out + (size_t)g * 8) = v;
}

__global__ __launch_bounds__(256) void pack_all(
    const float* __restrict__ Wv, const float* __restrict__ Ws,
    const float* __restrict__ Wa, const float* __restrict__ Wo,
    __hip_bfloat16* __restrict__ wv_p, __hip_bfloat16* __restrict__ wsa_p,
    __hip_bfloat16* __restrict__ wo_p) {
  const int b = blockIdx.x, t = threadIdx.x;
  if (b < 32)       pack_one(Wv, Wv, 256, 256, wv_p,  b * 256 + t);
  else if (b < 80)  pack_one(Ws, Wa, 256, 384, wsa_p, (b - 32) * 256 + t);
  else              pack_one(Wo, Wo, 256, 256, wo_p,  (b - 80) * 256 + t);
}

// ---- query locality sort: bin by level-0 reference point (32x32 per batch) ----
static __device__ __forceinline__ int bin_of(const float* refp, int b, int q) {
  const size_t base = (((size_t)b * NQ + q) * 4) * 2;  // level 0
  float rx = refp[base + 0], ry = refp[base + 1];
  int bx = (int)(rx * 32.f); bx = bx < 0 ? 0 : (bx > 31 ? 31 : bx);
  int by = (int)(ry * 32.f); by = by < 0 ? 0 : (by > 31 ? 31 : by);
  return b * 1024 + by * 32 + bx;
}

__global__ __launch_bounds__(256) void hist_k(
    const float* __restrict__ refp, unsigned int* __restrict__ hist) {
  int i = blockIdx.x * 256 + threadIdx.x;
  if (i >= 2 * NQ) return;
  int b = i >= NQ; int q = i - b * NQ;
  atomicAdd(&hist[bin_of(refp, b, q)], 1u);
}

__global__ __launch_bounds__(256) void scan_k(
    const unsigned int* __restrict__ hist, unsigned int* __restrict__ cursor) {
  __shared__ unsigned int lds[256];
  const int t = threadIdx.x;
  unsigned int v[8], s = 0;
#pragma unroll
  for (int j = 0; j < 8; ++j) { v[j] = hist[t * 8 + j]; s += v[j]; }
  lds[t] = s; __syncthreads();
  for (int off = 1; off < 256; off <<= 1) {
    unsigned int x = (t >= off) ? lds[t - off] : 0u;
    __syncthreads();
    lds[t] += x;
    __syncthreads();
  }
  unsigned int base = lds[t] - s;
#pragma unroll
  for (int j = 0; j < 8; ++j) { cursor[t * 8 + j] = base; base += v[j]; }
}

__global__ __launch_bounds__(256) void scatter_k(
    const float* __restrict__ refp, unsigned int* __restrict__ cursor,
    unsigned int* __restrict__ perm) {
  int i = blockIdx.x * 256 + threadIdx.x;
  if (i >= 2 * NQ) return;
  int b = i >= NQ; int q = i - b * NQ;
  unsigned int pos = atomicAdd(&cursor[bin_of(refp, b, q)], 1u);
  perm[pos] = (unsigned int)q;
}

// ---- 32-row-tile GEMM (modes 0/1) ----
#define CSTR 68

__global__ __launch_bounds__(128) void gemm_mt(
    const float* __restrict__ inpf, const float* __restrict__ query,
    const bf16x8* __restrict__ wv_p, const bf16x8* __restrict__ wsa_p,
    const float* __restrict__ bv, const float* __restrict__ bs,
    const float* __restrict__ ba,
    __hip_bfloat16* __restrict__ value, __half* __restrict__ params) {
  __shared__ bf16x8 As[8 * 2 * 64];        // 16 KB
  __shared__ float  Cs[2 * MT * CSTR];     // 17.4 KB

  const int t = threadIdx.x;
  const int bm = blockIdx.x * MT;
  const int lane = t & 63, wid = t >> 6;
  const int mode = blockIdx.y;

  {
    const int r = t >> 2;
    const int row = bm + r;
    const int sm = r >> 4;
    const int lb = r & 15;
    const bool ok = row < M_;
    const float* Af = (mode == 0) ? inpf : query;
    const float* ap = Af + (size_t)row * 256 + (t & 3) * 64;
#pragma unroll
    for (int gi = 0; gi < 8; ++gi) {
      float4 u = make_float4(0.f,0.f,0.f,0.f), v = make_float4(0.f,0.f,0.f,0.f);
      if (ok) { u = *(const float4*)(ap + gi * 8); v = *(const float4*)(ap + gi * 8 + 4); }
      bf16x8 w;
      w[0]=(__bf16)u.x; w[1]=(__bf16)u.y; w[2]=(__bf16)u.z; w[3]=(__bf16)u.w;
      w[4]=(__bf16)v.x; w[5]=(__bf16)v.y; w[6]=(__bf16)v.z; w[7]=(__bf16)v.w;
      int k8 = (t & 3) * 8 + gi;
      As[((k8 >> 2) * 2 + sm) * 64 + lb + ((k8 & 3) << 4)] = w;
    }
  }
  __syncthreads();

  const bf16x8* Bp = (mode == 0) ? wv_p : wsa_p;
  const int NB = (mode == 1) ? 6 : 4;
  float* Cw = &Cs[wid * MT * CSTR];

  for (int nb = wid; nb < NB; nb += 2) {
    const int colbase = nb * 64;
    const bf16x8* bpn = Bp + (size_t)nb * 2048;

    f32x4 acc[2][4] = {};
#pragma unroll
    for (int kt = 0; kt < 8; ++kt) {
      bf16x8 a0 = As[(kt * 2 + 0) * 64 + lane];
      bf16x8 a1 = As[(kt * 2 + 1) * 64 + lane];
#pragma unroll
      for (int n = 0; n < 4; ++n) {
        bf16x8 b = bpn[(kt * 4 + n) * 64 + lane];
        acc[0][n] = mfma16(a0, b, acc[0][n]);
        acc[1][n] = mfma16(a1, b, acc[1][n]);
      }
    }

#pragma unroll
    for (int m = 0; m < 2; ++m)
#pragma unroll
      for (int n = 0; n < 4; ++n)
#pragma unroll
        for (int rg = 0; rg < 4; ++rg)
          Cw[(m * 16 + (lane >> 4) * 4 + rg) * CSTR + n * 16 + (lane & 15)] = acc[m][n][rg];

    if (mode == 0) {
#pragma unroll
      for (int p = 0; p < 4; ++p) {
        const int r = (lane >> 3) + p * 8;
        const int c = (lane & 7) * 8;
        const int row = bm + r;
        float4 u = *(float4*)&Cw[r * CSTR + c];
        float4 v = *(float4*)&Cw[r * CSTR + c + 4];
        const float* bias = bv + colbase + c;
        bf16x8 o;
        o[0]=(__bf16)(u.x+bias[0]); o[1]=(__bf16)(u.y+bias[1]);
        o[2]=(__bf16)(u.z+bias[2]); o[3]=(__bf16)(u.w+bias[3]);
        o[4]=(__bf16)(v.x+bias[4]); o[5]=(__bf16)(v.y+bias[5]);
        o[6]=(__bf16)(v.z+bias[6]); o[7]=(__bf16)(v.w+bias[7]);
        if (row < M_)
          *(bf16x8*)(value + (size_t)row * 256 + colbase + c) = o;
      }
    } else {
#pragma unroll
      for (int p = 0; p < 8; ++p) {
        const int r = (lane >> 4) + p * 4;
        const int c = (lane & 15) * 4;
        const int row = bm + r;
        const int col = colbase + c;
        float4 u = *(float4*)&Cw[r * CSTR + c];
        const float* bias = (col < 256) ? (bs + col) : (ba + col - 256);
        u.x += bias[0]; u.y += bias[1]; u.z += bias[2]; u.w += bias[3];
        if (row < M_) {
          __half2 h0 = __floats2half2_rn(u.x, u.y);
          __half2 h1 = __floats2half2_rn(u.z, u.w);
          uint2 st;
          st.x = *(unsigned int*)&h0;
          st.y = *(unsigned int*)&h1;
          *(uint2*)(params + (size_t)row * 384 + col) = st;
        }
      }
    }
  }
}

// ---- fused sampler (sorted queries): build + gather + out-proj ----
// grid = 1664 1-D blocks: c=bid&7 -> batch=c>>2, sorted-range quarter=(c&3);
// qblock = (c&3)*208 + (bid>>3). Presumed bid%8 -> XCD round-robin gives each
// XCD one batch and a contiguous sorted range (L2 footprint < 4 MB).
#define CS 65
#define REGH (64 * CS)

__global__ __launch_bounds__(256) void sampler(
    const float* __restrict__ refp, const __half* __restrict__ params,
    const __hip_bfloat16* __restrict__ value, const bf16x8* __restrict__ wo_p,
    const float* __restrict__ bo, const unsigned int* __restrict__ perm,
    float* __restrict__ outp) {
  __shared__ unsigned int combo[2 * REGH];  // 33.3 KB
  __shared__ unsigned int qmap[16];

  const int c  = blockIdx.x & 7;
  const int kk = blockIdx.x >> 3;
  const int bb = c >> 2;
  const int qb = (c & 3) * 208 + kk;
  if (qb > 830) return;
  const int q0 = qb * 16;

  const int t = threadIdx.x;
  if (t < 16)
    qmap[t] = (q0 + t < NQ) ? perm[(size_t)bb * NQ + q0 + t] : 0xFFFFFFFFu;
  __syncthreads();

  const int cqi = t >> 5;          // build: query 0..7
  const int chh = (t >> 2) & 7;    // build: head
  const int cl  = t & 3;           // build: level

  const int lane = t & 63;
  const int wid  = t >> 6;
  const int q2   = lane >> 5;
  const int gh   = (lane >> 2) & 7;
  const int gs   = lane & 3;
  const char* vb = (const char*)value;
  const unsigned int voff0 = (unsigned int)bb * (NK * 512u) + (unsigned)(gh * 64 + gs * 16);

  const float DIMF[4]  = {100.f, 50.f, 25.f, 13.f};
  const int   LSTART[4] = {0, 10000, 12500, 13125};
  const float dimf  = DIMF[cl];
  const int   Wd    = (int)dimf;
  const int   lbase = LSTART[cl];

  for (int qc = 0; qc < 16; qc += 8) {
    unsigned int* reg = combo + ((qc >> 3) & 1) * REGH;
    // ---- build: one thread per (q, head, level) ----
    {
      const unsigned int qreal = qmap[qc + cqi];
      const bool valid = qreal != 0xFFFFFFFFu;
      const size_t row = (size_t)bb * NQ + (valid ? qreal : 0);
      const __half* pr = params + row * 384;

      union { uint4 u[2]; __half h[16]; } LG;
      LG.u[0] = *(const uint4*)(pr + 256 + chh * 16);
      LG.u[1] = *(const uint4*)(pr + 256 + chh * 16 + 8);
      float lgf[16];
#pragma unroll
      for (int j = 0; j < 16; ++j) lgf[j] = __half2float(LG.h[j]);
      float m = lgf[0];
#pragma unroll
      for (int j = 1; j < 16; ++j) m = fmaxf(m, lgf[j]);
      float s = 0.f;
#pragma unroll
      for (int j = 0; j < 16; ++j) s += __expf(lgf[j] - m);
      const float inv = valid ? 1.f / s : 0.f;

      const float rx = refp[(row * 4 + cl) * 2 + 0];
      const float ry = refp[(row * 4 + cl) * 2 + 1];
      union { uint4 u; __half h[8]; } OF;
      OF.u = *(const uint4*)(pr + chh * 32 + cl * 8);
      unsigned int* cb = &reg[(cqi * 8 + chh) * CS + cl * 16];

#pragma unroll
      for (int p = 0; p < 4; ++p) {
        const float wa = __expf(lgf[cl * 4 + p] - m) * inv;
        const float x = rx * dimf + __half2float(OF.h[p * 2 + 0]) - 0.5f;
        const float y = ry * dimf + __half2float(OF.h[p * 2 + 1]) - 0.5f;
        const float xf = floorf(x), yf = floorf(y);
        const float dx = x - xf, dy = y - yf;
        const int x0 = (int)xf, y0 = (int)yf;
        float w00 = (1.f - dx) * (1.f - dy) * wa;
        float w10 = dx * (1.f - dy) * wa;
        float w01 = (1.f - dx) * dy * wa;
        float w11 = dx * dy * wa;
        int i0, i1, i2, i3, xi, yi;
        xi = x0;     yi = y0;
        if (xi >= 0 && xi < Wd && yi >= 0 && yi < Wd) i0 = lbase + yi * Wd + xi; else { i0 = 0; w00 = 0.f; }
        xi = x0 + 1; yi = y0;
        if (xi >= 0 && xi < Wd && yi >= 0 && yi < Wd) i1 = lbase + yi * Wd + xi; else { i1 = 0; w10 = 0.f; }
        xi = x0;     yi = y0 + 1;
        if (xi >= 0 && xi < Wd && yi >= 0 && yi < Wd) i2 = lbase + yi * Wd + xi; else { i2 = 0; w01 = 0.f; }
        xi = x0 + 1; yi = y0 + 1;
        if (xi >= 0 && xi < Wd && yi >= 0 && yi < Wd) i3 = lbase + yi * Wd + xi; else { i3 = 0; w11 = 0.f; }
        cb[p * 4 + 0] = ((__float_as_uint(w00) + 0x8000u) & 0xffff0000u) | (unsigned)i0;
        cb[p * 4 + 1] = ((__float_as_uint(w10) + 0x8000u) & 0xffff0000u) | (unsigned)i1;
        cb[p * 4 + 2] = ((__float_as_uint(w01) + 0x8000u) & 0xffff0000u) | (unsigned)i2;
        cb[p * 4 + 3] = ((__float_as_uint(w11) + 0x8000u) & 0xffff0000u) | (unsigned)i3;
      }
    }
    __syncthreads();

    // ---- gather ----
    {
      const int qw = wid * 2 + q2;
      const int rr = qw * 8 + gh;
      const unsigned int* cb = &reg[rr * CS];
      float a0=0.f,a1=0.f,a2=0.f,a3=0.f,a4=0.f,a5=0.f,a6=0.f,a7=0.f;
#pragma unroll 8
      for (int e = 0; e < 64; ++e) {
        const unsigned int u = cb[e];
        const float w = __uint_as_float(u & 0xffff0000u);
        const unsigned int voff = voff0 + ((u & 0xffffu) << 9);
        const uint4 v = *(const uint4*)(vb + (size_t)voff);
        a0 += w * __uint_as_float(v.x << 16);
        a1 += w * __uint_as_float(v.x & 0xffff0000u);
        a2 += w * __uint_as_float(v.y << 16);
        a3 += w * __uint_as_float(v.y & 0xffff0000u);
        a4 += w * __uint_as_float(v.z << 16);
        a5 += w * __uint_as_float(v.z & 0xffff0000u);
        a6 += w * __uint_as_float(v.w << 16);
        a7 += w * __uint_as_float(v.w & 0xffff0000u);
      }
      bf16x8 o;
      o[0]=(__bf16)a0; o[1]=(__bf16)a1; o[2]=(__bf16)a2; o[3]=(__bf16)a3;
      o[4]=(__bf16)a4; o[5]=(__bf16)a5; o[6]=(__bf16)a6; o[7]=(__bf16)a7;
      const int s = (4 - (rr & 3)) & 3;
      *(bf16x8*)(&reg[rr * CS + s + gs * 4]) = o;
    }
  }
  __syncthreads();

  // ---- fused out-projection: out[16 x 256] = accs @ Wo + bo ----
  {
    const unsigned int* abase = combo + ((lane >> 3) & 1) * REGH
                              + (lane & 7) * (8 * CS) + (lane >> 4) * 4;
    const bf16x8* bpn = wo_p + (size_t)wid * 2048;
    f32x4 oacc[4] = {};
#pragma unroll
    for (int kt = 0; kt < 8; ++kt) {
      const int s = (4 - (kt & 3)) & 3;
      bf16x8 a = *(const bf16x8*)(abase + kt * CS + s);
#pragma unroll
      for (int n = 0; n < 4; ++n)
        oacc[n] = mfma16(a, bpn[(kt * 4 + n) * 64 + lane], oacc[n]);
    }
#pragma unroll
    for (int n = 0; n < 4; ++n) {
      const int col = wid * 64 + n * 16 + (lane & 15);
      const float bias = bo[col];
#pragma unroll
      for (int rg = 0; rg < 4; ++rg) {
        const int ql = (lane >> 4) * 4 + rg;
        const unsigned int qreal = qmap[ql];
        if (qreal != 0xFFFFFFFFu)
          outp[((size_t)bb * NQ + qreal) * 256 + col] = oacc[n][rg] + bias;
      }
    }
  }
}

extern "C" void kernel_launch(void* const* d_in, const int* in_sizes, int n_in,
                              void* d_out, int out_size, void* d_ws, size_t ws_size,
                              hipStream_t stream) {
  const float* query = (const float*)d_in[0];
  const float* refp  = (const float*)d_in[1];
  const float* inpf  = (const float*)d_in[2];
  const float* Wv    = (const float*)d_in[3];
  const float* bv    = (const float*)d_in[4];
  const float* Ws    = (const float*)d_in[5];
  const float* bs    = (const float*)d_in[6];
  const float* Wa    = (const float*)d_in[7];
  const float* ba    = (const float*)d_in[8];
  const float* Wo    = (const float*)d_in[9];
  const float* bo    = (const float*)d_in[10];
  float* out = (float*)d_out;

  char* w = (char*)d_ws;
  __hip_bfloat16* value  = (__hip_bfloat16*)w;            w += (size_t)M_ * 256 * 2;  // key-major
  __half*         params = (__half*)w;                    w += (size_t)M_ * 384 * 2;
  __hip_bfloat16* wv_p   = (__hip_bfloat16*)w;            w += 256 * 256 * 2;
  __hip_bfloat16* wsa_p  = (__hip_bfloat16*)w;            w += 256 * 384 * 2;
  __hip_bfloat16* wo_p   = (__hip_bfloat16*)w;            w += 256 * 256 * 2;
  unsigned int*   hist   = (unsigned int*)w;              w += 2048 * 4;
  unsigned int*   cursor = (unsigned int*)w;              w += 2048 * 4;
  unsigned int*   perm   = (unsigned int*)w;

  hipMemsetAsync(hist, 0, 2048 * 4, stream);

  const int sg = (2 * NQ + 255) / 256;  // 104
  hist_k<<<sg, 256, 0, stream>>>(refp, hist);
  scan_k<<<1, 256, 0, stream>>>(hist, cursor);
  scatter_k<<<sg, 256, 0, stream>>>(refp, cursor, perm);

  pack_all<<<112, 256, 0, stream>>>(Wv, Ws, Wa, Wo, wv_p, wsa_p, wo_p);

  gemm_mt<<<dim3(GX, 2), 128, 0, stream>>>(
      inpf, query, (const bf16x8*)wv_p, (const bf16x8*)wsa_p,
      bv, bs, ba, value, params);

  sampler<<<1664, 256, 0, stream>>>(refp, params, value,
                                    (const bf16x8*)wo_p, bo, perm, out);
}